// Round 8
// baseline (3589.598 us; speedup 1.0000x reference)
//
#include <hip/hip_runtime.h>
#include <stdint.h>

typedef unsigned short u16;
typedef short v8s __attribute__((ext_vector_type(8)));
typedef short v4s __attribute__((ext_vector_type(4)));
typedef float v4f __attribute__((ext_vector_type(4)));

#define NB 32768
#define ND 256
#define DTF (1.0f/3.0f)
#define ALPHA 0.1f
#define DECAY 0.99f
#define TAU_MIN 0.2f
#define HEBB_SCALE (0.1f*(1.0f/3.0f)/32768.0f)

__device__ __forceinline__ float b2f(u16 h){ return __uint_as_float(((unsigned)h)<<16); }
__device__ __forceinline__ u16 f2b(float f){
  unsigned u = __float_as_uint(f);
  u += 0x7FFFu + ((u>>16)&1u);
  return (u16)(u>>16);
}

__device__ __forceinline__ void async16(const void* g, void* l){
  __builtin_amdgcn_global_load_lds((const __attribute__((address_space(1))) unsigned*)g,
                                   (__attribute__((address_space(3))) unsigned*)l, 16, 0, 0);
}

__device__ __forceinline__ void waitv(int n){
  switch(n){
    case 8: asm volatile("s_waitcnt vmcnt(8)" ::: "memory"); break;
    case 4: asm volatile("s_waitcnt vmcnt(4)" ::: "memory"); break;
    case 3: asm volatile("s_waitcnt vmcnt(3)" ::: "memory"); break;
    case 2: asm volatile("s_waitcnt vmcnt(2)" ::: "memory"); break;
    default: asm volatile("s_waitcnt vmcnt(0)" ::: "memory"); break;
  }
}

// ---------------- init: x,h -> bf16; x -> xT (fused) ----------------
__global__ void k_init(const float* __restrict__ x, const float* __restrict__ h,
                       u16* __restrict__ x_bf, u16* __restrict__ h_bf,
                       u16* __restrict__ xT){
  __shared__ u16 lt[256*68];
  const long r0 = (long)blockIdx.x*64;
  const int t = threadIdx.x;
#pragma unroll
  for (int e=0; e<16; ++e){
    int i = e*1024 + t*4;
    int row = i>>8, col = i&255;
    v4f xv = *(const v4f*)(x + (r0+row)*ND + col);
    v4f hv = *(const v4f*)(h + (r0+row)*ND + col);
    u16 a4[4], b4[4];
#pragma unroll
    for (int k=0;k<4;++k){ a4[k]=f2b(xv[k]); b4[k]=f2b(hv[k]); }
    *(v4s*)(x_bf + (r0+row)*ND + col) = *(v4s*)a4;
    *(v4s*)(h_bf + (r0+row)*ND + col) = *(v4s*)b4;
#pragma unroll
    for (int k=0;k<4;++k) lt[(col+k)*68 + row] = a4[k];
  }
  __syncthreads();
#pragma unroll
  for (int e=0; e<16; ++e)
    *(v4s*)(xT + (long)t*NB + r0 + e*4) = *(v4s*)&lt[t*68 + e*4];
}

// ---------------- weight prep (bf16 [n][k]) ----------------
__global__ void k_prep_w(const float* __restrict__ W_ih, const float* __restrict__ W_hh,
                         const float* __restrict__ W_t1, const float* __restrict__ W_t2,
                         const float* __restrict__ hebb_ih, const float* __restrict__ hebb_hh,
                         u16* __restrict__ weff_ih, u16* __restrict__ weff_hh,
                         u16* __restrict__ wt1a, u16* __restrict__ wt1b, u16* __restrict__ wt2){
  int i = blockIdx.x*blockDim.x + threadIdx.x;
  if (i >= ND*ND) return;
  int n = i >> 8, k = i & 255;
  weff_ih[i] = f2b(W_ih[i] + ALPHA*hebb_ih[k*ND + n]);
  weff_hh[i] = f2b(W_hh[i] + ALPHA*hebb_hh[k*ND + n]);
  wt1a[i] = f2b(W_t1[n*512 + k]);
  wt1b[i] = f2b(W_t1[n*512 + 256 + k]);
  wt2[i]  = f2b(W_t2[i]);
}

// ---------------- P = x @ W_t1a^T + b_t1  (bf16 out) ----------------
__launch_bounds__(512,2)
__global__ void k_gemmP(const u16* __restrict__ x_bf, const u16* __restrict__ wt1a,
                        const float* __restrict__ b_t1, u16* __restrict__ P){
  __shared__ u16 lA[128*40];
  __shared__ u16 lB[256*40];
  int t = threadIdx.x, lid = t&63, wid = t>>6, wm = wid>>2, wn = wid&3, lr = lid&15, lg = lid>>4;
  long row0 = (long)blockIdx.x*128;
  v4f z = {0.f,0.f,0.f,0.f};
  v4f acc[4][4];
#pragma unroll
  for (int a=0;a<4;++a)
#pragma unroll
    for (int b=0;b<4;++b) acc[a][b] = z;
  for (int c=0; c<8; ++c){
    __syncthreads();
    { int r=t>>2, sg=t&3;
      *(v8s*)&lA[r*40+sg*8] = *(const v8s*)(x_bf + (row0+r)*ND + c*32 + sg*8); }
#pragma unroll
    for (int it2=0; it2<2; ++it2){
      int s2=t+it2*512; int n=s2>>2, sg=s2&3;
      *(v8s*)&lB[n*40+sg*8] = *(const v8s*)(wt1a + n*ND + c*32 + sg*8);
    }
    __syncthreads();
    v8s a[4], b[4];
#pragma unroll
    for (int mf=0;mf<4;++mf) a[mf] = *(v8s*)&lA[(wm*64+mf*16+lr)*40 + lg*8];
#pragma unroll
    for (int nf=0;nf<4;++nf) b[nf] = *(v8s*)&lB[(wn*64+nf*16+lr)*40 + lg*8];
#pragma unroll
    for (int mf=0;mf<4;++mf)
#pragma unroll
      for (int nf=0;nf<4;++nf)
        acc[mf][nf] = __builtin_amdgcn_mfma_f32_16x16x32_bf16(a[mf], b[nf], acc[mf][nf], 0,0,0);
  }
#pragma unroll
  for (int mf=0;mf<4;++mf)
#pragma unroll
    for (int nf=0;nf<4;++nf)
#pragma unroll
      for (int r=0;r<4;++r){
        int rr = wm*64+mf*16+lg*4+r, cc = wn*64+nf*16+lr;
        P[(row0+rr)*ND + cc] = f2b(acc[mf][nf][r] + b_t1[cc]);
      }
}

// ---------------- fused dynamics + RK update: 128-row tile, ring-3 lead-2 ----
// jobs 0-7: ev@wt1b -> acc2 ; 8-15: x@weff_ih -> accI ; 16-23: ev@weff_hh -> accI
// 24-31: u@wt2 -> acc4 (u from lU).  Grid = 256 (1 block/CU, single pass).
template<int BASEF, int WF, int WT, int WB>
__launch_bounds__(512,2)
__global__ void k_dyn4(const u16* __restrict__ x_bf, const u16* __restrict__ ev_bf,
                       const float* __restrict__ baseF,
                       const u16* __restrict__ weff_ih, const u16* __restrict__ weff_hh,
                       const u16* __restrict__ wt1b, const u16* __restrict__ wt2,
                       const u16* __restrict__ P,
                       const float* __restrict__ b_ih, const float* __restrict__ b_hh,
                       const float* __restrict__ b_t2, float coef,
                       float* __restrict__ outF, u16* __restrict__ outB, u16* __restrict__ outT){
  __shared__ u16 lA[3*4096];       // 3 x [128][32] linear (gload_lds dest)
  __shared__ u16 lB[3*8192];       // 3 x [256][32] linear
  __shared__ u16 lU[128*272];      // u panel [128][272] XOR; reused [256][136] / [128][256] bounce
  __shared__ float sb1[256], sb2[256];
  const int t = threadIdx.x, lid = t&63, wid = t>>6;
  const int wm = wid>>2, wn = wid&3, lr = lid&15, lg = lid>>4;
  const long row0 = (long)blockIdx.x*128;

  if (t < 256){ sb1[t] = b_ih[t] + b_hh[t]; sb2[t] = b_t2[t]; }

  // staging source offsets (chunk-XOR pre-swizzled on the GLOBAL side)
  const int rA  = wid*16 + (lid>>2);                   // 0..127
  const long aoffg = (row0 + rA)*ND + (((lid&3) ^ ((rA>>1)&3))*8);
  const int rB0 = wid*32 + (lid>>2), rB1 = rB0 + 16;
  const int boffg0 = rB0*ND + (((lid&3) ^ ((rB0>>1)&3))*8);
  const int boffg1 = rB1*ND + (((lid&3) ^ ((rB1>>1)&3))*8);

  // fragment read offsets (u16 index within a slot), same XOR on the read side
  int aoff[4], boff[4], uoff[4];
#pragma unroll
  for (int mf=0;mf<4;++mf){
    int R = wm*64 + mf*16 + lr;
    aoff[mf] = R*32 + ((lg ^ ((R>>1)&3))*8);
    uoff[mf] = R*272 + ((lg ^ ((R>>1)&3))*8);
  }
#pragma unroll
  for (int nf=0;nf<4;++nf){
    int N = wn*64 + nf*16 + lr;
    boff[nf] = N*32 + ((lg ^ ((N>>1)&3))*8);
  }

  auto stage = [&](int jj, int sl){
    const int c = (jj&7)*32;
    if (jj < 24){
      const u16* asrc = (jj<8) ? ev_bf : (jj<16 ? x_bf : ev_bf);
      async16(asrc + aoffg + c, lA + sl*4096 + wid*512);
    }
    const u16* W = (jj<8) ? wt1b : (jj<16 ? weff_ih : (jj<24 ? weff_hh : wt2));
    async16(W + c + boffg0, lB + sl*8192 + wid*1024);
    async16(W + c + boffg1, lB + sl*8192 + wid*1024 + 512);
  };

  // prologue: jobs 0,1 staged; P prefetch; full drain
  stage(0,0); stage(1,1);
  u16 Pv[64];
#pragma unroll
  for (int mf=0;mf<4;++mf)
#pragma unroll
    for (int nf=0;nf<4;++nf)
#pragma unroll
      for (int r=0;r<4;++r){
        int rr = wm*64+mf*16+lg*4+r, cc = wn*64+nf*16+lr;
        Pv[(mf*4+nf)*4+r] = P[(row0+rr)*ND + cc];
      }
  __syncthreads();

  v4f z = {0.f,0.f,0.f,0.f};
  v4f acc2[4][4], accI[4][4], acc4[4][4];
#pragma unroll
  for (int a=0;a<4;++a)
#pragma unroll
    for (int b=0;b<4;++b){ acc2[a][b]=z; accI[a][b]=z; acc4[a][b]=z; }

#pragma unroll
  for (int j=0; j<32; ++j){
    // wait for job j's loads (issued at j-2); keep job j+1's in flight
    waitv(j<=22 ? 3 : (j<=30 ? 2 : 0));
    __builtin_amdgcn_s_barrier();
    if (j <= 29) stage(j+2, (j+2)%3);

    const int rs = j%3;
    v8s b[4];
#pragma unroll
    for (int nf=0;nf<4;++nf) b[nf] = *(v8s*)&lB[rs*8192 + boff[nf]];
    v8s a[4];
    if (j < 24){
#pragma unroll
      for (int mf=0;mf<4;++mf) a[mf] = *(v8s*)&lA[rs*4096 + aoff[mf]];
    } else {
#pragma unroll
      for (int mf=0;mf<4;++mf) a[mf] = *(v8s*)&lU[uoff[mf] + (j&7)*32];
    }

    __builtin_amdgcn_s_setprio(1);
    if (j < 8){
#pragma unroll
      for (int mf=0;mf<4;++mf)
#pragma unroll
        for (int nf=0;nf<4;++nf)
          acc2[mf][nf] = __builtin_amdgcn_mfma_f32_16x16x32_bf16(a[mf], b[nf], acc2[mf][nf], 0,0,0);
    } else if (j < 24){
#pragma unroll
      for (int mf=0;mf<4;++mf)
#pragma unroll
        for (int nf=0;nf<4;++nf)
          accI[mf][nf] = __builtin_amdgcn_mfma_f32_16x16x32_bf16(a[mf], b[nf], accI[mf][nf], 0,0,0);
    } else {
#pragma unroll
      for (int mf=0;mf<4;++mf)
#pragma unroll
        for (int nf=0;nf<4;++nf)
          acc4[mf][nf] = __builtin_amdgcn_mfma_f32_16x16x32_bf16(a[mf], b[nf], acc4[mf][nf], 0,0,0);
    }
    __builtin_amdgcn_s_setprio(0);

    if (j == 7){
      // u = SiLU(acc2 + P) -> lU [128][272] with chunk-XOR per row-pair
#pragma unroll
      for (int mf=0;mf<4;++mf)
#pragma unroll
        for (int nf=0;nf<4;++nf)
#pragma unroll
          for (int r=0;r<4;++r){
            int rr = wm*64+mf*16+lg*4+r, cc = wn*64+nf*16+lr;
            float v = acc2[mf][nf][r] + b2f(Pv[(mf*4+nf)*4+r]);
            float sgm = 1.f/(1.f + __expf(-v));
            int w = cc>>5, ch = (cc>>3)&3;
            lU[rr*272 + w*32 + ((ch ^ ((rr>>1)&3))*8) + (cc&7)] = f2b(v*sgm);
          }
      asm volatile("s_waitcnt lgkmcnt(0)" ::: "memory");
    }
  }

  __syncthreads();   // all lU phase-4 reads done (before bounce reuse)

  // epilogue: inter = tanh(accI + b), tau = softplus(acc4 + b_t2) + TAU_MIN
  float ov[64];
#pragma unroll
  for (int mf=0;mf<4;++mf)
#pragma unroll
    for (int nf=0;nf<4;++nf)
#pragma unroll
      for (int r=0;r<4;++r){
        int rr = wm*64+mf*16+lg*4+r, cc = wn*64+nf*16+lr;
        long gi = (row0+rr)*ND + cc;
        float pre = accI[mf][nf][r] + sb1[cc];
        float pc = fminf(fmaxf(pre, -15.f), 15.f);
        float e2 = __expf(2.f*pc);
        float inter = (e2 - 1.f)/(e2 + 1.f);
        float zz = acc4[mf][nf][r] + sb2[cc];
        float sp = (zz > 15.f) ? zz : __logf(1.f + __expf(zz));
        float tau = sp + TAU_MIN;
        float bv, ev;
        if (BASEF){ bv = baseF[gi]; ev = b2f(ev_bf[gi]); }
        else      { bv = b2f(ev_bf[gi]); ev = bv; }
        float o = bv + coef*(inter - ev)/tau;
        if (WF) outF[gi] = o;
        ov[(mf*4+nf)*4+r] = o;
      }

  if (WT){
    // transpose bounce: lU as [256 cols][136 rows]
#pragma unroll
    for (int mf=0;mf<4;++mf)
#pragma unroll
      for (int nf=0;nf<4;++nf)
#pragma unroll
        for (int r=0;r<4;++r){
          int rr = wm*64+mf*16+lg*4+r, cc = wn*64+nf*16+lr;
          lU[cc*136 + rr] = f2b(ov[(mf*4+nf)*4+r]);
        }
    __syncthreads();
    { int col = t>>1, h0 = (t&1)*64;
#pragma unroll
      for (int e=0;e<8;++e)
        *(v8s*)(outT + (long)col*NB + row0 + h0 + e*8) = *(v8s*)&lU[col*136 + h0 + e*8];
    }
  }
  if (WB){
    // row-major bounce: lU as [128][256]
    if (WT) __syncthreads();
#pragma unroll
    for (int mf=0;mf<4;++mf)
#pragma unroll
      for (int nf=0;nf<4;++nf)
#pragma unroll
        for (int r=0;r<4;++r){
          int rr = wm*64+mf*16+lg*4+r, cc = wn*64+nf*16+lr;
          lU[rr*256 + cc] = f2b(ov[(mf*4+nf)*4+r]);
        }
    __syncthreads();
    { int row = t>>2, c0 = (t&3)*64;
#pragma unroll
      for (int e=0;e<8;++e)
        *(v8s*)(outB + (row0 + row)*ND + c0 + e*8) = *(v8s*)&lU[row*256 + c0 + e*8];
    }
  }
}

// ---------------- hebb partial: part[blk] = A^T-chunk @ hm-chunk (pipelined) --
__launch_bounds__(512,2)
__global__ void k_hebb_part2(const u16* __restrict__ xT, const u16* __restrict__ hmT,
                             u16* __restrict__ part){
  __shared__ u16 lA[4*8192];    // 4 x [256][32]
  __shared__ u16 lB[4*8192];
  const int t = threadIdx.x, lid = t&63, wid = t>>6;
  const int wm = wid>>2, wn = wid&3, lr = lid&15, lg = lid>>4;
  const int mat = blockIdx.x & 1, chunk = blockIdx.x >> 1;   // 128 chunks x 2 mats
  const u16* Asrc = mat ? hmT : xT;
  const long col0 = (long)chunk*256;

  const int r0s = wid*32 + (lid>>2), r1s = r0s + 16;
  const long goff0 = (long)r0s*NB + (((lid&3) ^ ((r0s>>1)&3))*8);
  const long goff1 = (long)r1s*NB + (((lid&3) ^ ((r1s>>1)&3))*8);

  int aoff[8], boff[4];
#pragma unroll
  for (int mf=0;mf<8;++mf){
    int R = wm*128 + mf*16 + lr;
    aoff[mf] = R*32 + ((lg ^ ((R>>1)&3))*8);
  }
#pragma unroll
  for (int nf=0;nf<4;++nf){
    int N = wn*64 + nf*16 + lr;
    boff[nf] = N*32 + ((lg ^ ((N>>1)&3))*8);
  }

  auto stage = [&](int kc, int sl){
    const long c = col0 + kc*32;
    async16(Asrc + goff0 + c, lA + sl*8192 + wid*1024);
    async16(Asrc + goff1 + c, lA + sl*8192 + wid*1024 + 512);
    async16(hmT  + goff0 + c, lB + sl*8192 + wid*1024);
    async16(hmT  + goff1 + c, lB + sl*8192 + wid*1024 + 512);
  };

  stage(0,0); stage(1,1); stage(2,2);
  __syncthreads();

  v4f z = {0.f,0.f,0.f,0.f};
  v4f acc[8][4];
#pragma unroll
  for (int a=0;a<8;++a)
#pragma unroll
    for (int b=0;b<4;++b) acc[a][b] = z;

#pragma unroll
  for (int j=0; j<8; ++j){
    int m2 = 7-j; if (m2 > 2) m2 = 2;
    waitv(m2*4);
    __builtin_amdgcn_s_barrier();
    if (j <= 4) stage(j+3, (j+3)&3);
    const int rs = j&3;
    v8s a[8], b[4];
#pragma unroll
    for (int mf=0;mf<8;++mf) a[mf] = *(v8s*)&lA[rs*8192 + aoff[mf]];
#pragma unroll
    for (int nf=0;nf<4;++nf) b[nf] = *(v8s*)&lB[rs*8192 + boff[nf]];
    __builtin_amdgcn_s_setprio(1);
#pragma unroll
    for (int mf=0;mf<8;++mf)
#pragma unroll
      for (int nf=0;nf<4;++nf)
        acc[mf][nf] = __builtin_amdgcn_mfma_f32_16x16x32_bf16(a[mf], b[nf], acc[mf][nf], 0,0,0);
    __builtin_amdgcn_s_setprio(0);
  }

  u16* dst = part + (long)blockIdx.x*65536;
#pragma unroll
  for (int mf=0;mf<8;++mf)
#pragma unroll
    for (int nf=0;nf<4;++nf)
#pragma unroll
      for (int r=0;r<4;++r){
        int i = wm*128+mf*16+lg*4+r, jj = wn*64+nf*16+lr;
        dst[i*ND + jj] = f2b(acc[mf][nf][r]);
      }
}

// ---------------- hebb reduce + Weff rebuild ----------------
__global__ void k_hebb_reduce(const u16* __restrict__ part,
                              const float* __restrict__ prev_ih, const float* __restrict__ prev_hh,
                              float* __restrict__ next_ih, float* __restrict__ next_hh,
                              const float* __restrict__ W_ih, const float* __restrict__ W_hh,
                              u16* __restrict__ weff_ih, u16* __restrict__ weff_hh){
  int tid = blockIdx.x*blockDim.x + threadIdx.x;
  if (tid >= 2*ND*ND) return;
  int mat = tid >> 16;
  int rem = tid & 65535;
  float s = 0.f;
  for (int c=0; c<128; ++c) s += b2f(part[(long)((c<<1)+mat)*65536 + rem]);
  const float* prev = mat ? prev_hh : prev_ih;
  float nv = DECAY*prev[rem] + HEBB_SCALE*s;
  if (mat) next_hh[rem] = nv; else next_ih[rem] = nv;
  int k = rem >> 8, n = rem & 255;
  const float* Wb = mat ? W_hh : W_ih;
  u16 wv = f2b(Wb[n*ND + k] + ALPHA*nv);
  if (mat) weff_hh[n*ND + k] = wv; else weff_ih[n*ND + k] = wv;
}

// ---------------- launcher ----------------
extern "C" void kernel_launch(void* const* d_in, const int* in_sizes, int n_in,
                              void* d_out, int out_size, void* d_ws, size_t ws_size,
                              hipStream_t stream) {
  const float* x       = (const float*)d_in[0];
  const float* h       = (const float*)d_in[1];
  const float* hebb_ih = (const float*)d_in[2];
  const float* hebb_hh = (const float*)d_in[3];
  const float* W_ih    = (const float*)d_in[4];
  const float* b_ih    = (const float*)d_in[5];
  const float* W_hh    = (const float*)d_in[6];
  const float* b_hh    = (const float*)d_in[7];
  const float* W_t1    = (const float*)d_in[8];
  const float* b_t1    = (const float*)d_in[9];
  const float* W_t2    = (const float*)d_in[10];
  const float* b_t2    = (const float*)d_in[11];
  float* h_state = (float*)d_out;

  char* w = (char*)d_ws;
  u16* x_bf  = (u16*)w;  w += 16777216;
  u16* xT    = (u16*)w;  w += 16777216;
  u16* P     = (u16*)w;  w += 16777216;
  u16* hmT   = (u16*)w;  w += 16777216;
  u16* h_bf  = (u16*)w;  w += 16777216;
  u16* hm_bf = (u16*)w;  w += 16777216;
  u16* part  = (u16*)w;  w += 33554432;     // 256 slabs x 64K x 2B
  float* hebA_ih = (float*)w; w += 262144;
  float* hebA_hh = (float*)w; w += 262144;
  float* hebB_ih = (float*)w; w += 262144;
  float* hebB_hh = (float*)w; w += 262144;
  u16* weff_ih = (u16*)w; w += 131072;
  u16* weff_hh = (u16*)w; w += 131072;
  u16* wt1a    = (u16*)w; w += 131072;
  u16* wt1b    = (u16*)w; w += 131072;
  u16* wt2     = (u16*)w; w += 131072;
  if ((size_t)(w - (char*)d_ws) > ws_size) return;

  k_init<<<512,256,0,stream>>>(x, h, x_bf, h_bf, xT);
  k_prep_w<<<256,256,0,stream>>>(W_ih,W_hh,W_t1,W_t2,hebb_ih,hebb_hh,
                                 weff_ih,weff_hh,wt1a,wt1b,wt2);
  k_gemmP<<<256,512,0,stream>>>(x_bf, wt1a, b_t1, P);

  const float* pih = hebb_ih; const float* phh = hebb_hh;
  for (int s=0; s<3; ++s){
    float* nih = (s&1) ? hebB_ih : hebA_ih;
    float* nhh = (s&1) ? hebB_hh : hebA_hh;
    // k1: h_mid = h + 0.5*DT*dynamics(h)  (bf16 state path; writes hm_bf + hmT)
    k_dyn4<0,0,1,1><<<256,512,0,stream>>>(x_bf, h_bf, (const float*)0,
                                          weff_ih, weff_hh, wt1b, wt2, P,
                                          b_ih, b_hh, b_t2, 0.5f*DTF,
                                          (float*)0, hm_bf, hmT);
    // hebb updates + Weff rebuild
    k_hebb_part2<<<256,512,0,stream>>>(xT, hmT, part);
    k_hebb_reduce<<<512,256,0,stream>>>(part, pih, phh, nih, nhh, W_ih, W_hh, weff_ih, weff_hh);
    // k2: h = h + DT*dynamics(h_mid)  (baseF = h input on step 0, else h_state)
    const float* base = (s==0) ? h : (const float*)h_state;
    if (s < 2)
      k_dyn4<1,1,0,1><<<256,512,0,stream>>>(x_bf, hm_bf, base,
                                            weff_ih, weff_hh, wt1b, wt2, P,
                                            b_ih, b_hh, b_t2, DTF,
                                            h_state, h_bf, (u16*)0);
    else
      k_dyn4<1,1,0,0><<<256,512,0,stream>>>(x_bf, hm_bf, base,
                                            weff_ih, weff_hh, wt1b, wt2, P,
                                            b_ih, b_hh, b_t2, DTF,
                                            h_state, (u16*)0, (u16*)0);
    pih = nih; phh = nhh;
  }
}

// Round 9
// 592.073 us; speedup vs baseline: 6.0628x; 6.0628x over previous
//
#include <hip/hip_runtime.h>
#include <stdint.h>

typedef unsigned short u16;
typedef short v8s __attribute__((ext_vector_type(8)));
typedef short v4s __attribute__((ext_vector_type(4)));
typedef float v4f __attribute__((ext_vector_type(4)));

#define NB 32768
#define ND 256
#define DTF (1.0f/3.0f)
#define ALPHA 0.1f
#define DECAY 0.99f
#define TAU_MIN 0.2f
#define HEBB_SCALE (0.1f*(1.0f/3.0f)/32768.0f)

__device__ __forceinline__ float b2f(u16 h){ return __uint_as_float(((unsigned)h)<<16); }
__device__ __forceinline__ u16 f2b(float f){
  unsigned u = __float_as_uint(f);
  u += 0x7FFFu + ((u>>16)&1u);
  return (u16)(u>>16);
}

__device__ __forceinline__ void async16(const void* g, void* l){
  __builtin_amdgcn_global_load_lds((const __attribute__((address_space(1))) unsigned*)g,
                                   (__attribute__((address_space(3))) unsigned*)l, 16, 0, 0);
}

__device__ __forceinline__ void waitv(int n){
  switch(n){
    case 8: asm volatile("s_waitcnt vmcnt(8)" ::: "memory"); break;
    case 6: asm volatile("s_waitcnt vmcnt(6)" ::: "memory"); break;
    case 4: asm volatile("s_waitcnt vmcnt(4)" ::: "memory"); break;
    case 3: asm volatile("s_waitcnt vmcnt(3)" ::: "memory"); break;
    case 2: asm volatile("s_waitcnt vmcnt(2)" ::: "memory"); break;
    default: asm volatile("s_waitcnt vmcnt(0)" ::: "memory"); break;
  }
}

// ---------------- init: x,h -> bf16; x -> xT (fused) ----------------
__global__ void k_init(const float* __restrict__ x, const float* __restrict__ h,
                       u16* __restrict__ x_bf, u16* __restrict__ h_bf,
                       u16* __restrict__ xT){
  __shared__ u16 lt[256*68];
  const long r0 = (long)blockIdx.x*64;
  const int t = threadIdx.x;
#pragma unroll
  for (int e=0; e<16; ++e){
    int i = e*1024 + t*4;
    int row = i>>8, col = i&255;
    v4f xv = *(const v4f*)(x + (r0+row)*ND + col);
    v4f hv = *(const v4f*)(h + (r0+row)*ND + col);
    u16 a4[4], b4[4];
#pragma unroll
    for (int k=0;k<4;++k){ a4[k]=f2b(xv[k]); b4[k]=f2b(hv[k]); }
    *(v4s*)(x_bf + (r0+row)*ND + col) = *(v4s*)a4;
    *(v4s*)(h_bf + (r0+row)*ND + col) = *(v4s*)b4;
#pragma unroll
    for (int k=0;k<4;++k) lt[(col+k)*68 + row] = a4[k];
  }
  __syncthreads();
#pragma unroll
  for (int e=0; e<16; ++e)
    *(v4s*)(xT + (long)t*NB + r0 + e*4) = *(v4s*)&lt[t*68 + e*4];
}

// ---------------- weight prep (bf16 [n][k]) ----------------
__global__ void k_prep_w(const float* __restrict__ W_ih, const float* __restrict__ W_hh,
                         const float* __restrict__ W_t1, const float* __restrict__ W_t2,
                         const float* __restrict__ hebb_ih, const float* __restrict__ hebb_hh,
                         u16* __restrict__ weff_ih, u16* __restrict__ weff_hh,
                         u16* __restrict__ wt1a, u16* __restrict__ wt1b, u16* __restrict__ wt2){
  int i = blockIdx.x*blockDim.x + threadIdx.x;
  if (i >= ND*ND) return;
  int n = i >> 8, k = i & 255;
  weff_ih[i] = f2b(W_ih[i] + ALPHA*hebb_ih[k*ND + n]);
  weff_hh[i] = f2b(W_hh[i] + ALPHA*hebb_hh[k*ND + n]);
  wt1a[i] = f2b(W_t1[n*512 + k]);
  wt1b[i] = f2b(W_t1[n*512 + 256 + k]);
  wt2[i]  = f2b(W_t2[i]);
}

// ---------------- P = x @ W_t1a^T + b_t1  (bf16 out) ----------------
__launch_bounds__(512,2)
__global__ void k_gemmP(const u16* __restrict__ x_bf, const u16* __restrict__ wt1a,
                        const float* __restrict__ b_t1, u16* __restrict__ P){
  __shared__ u16 lA[128*40];
  __shared__ u16 lB[256*40];
  int t = threadIdx.x, lid = t&63, wid = t>>6, wm = wid>>2, wn = wid&3, lr = lid&15, lg = lid>>4;
  long row0 = (long)blockIdx.x*128;
  v4f z = {0.f,0.f,0.f,0.f};
  v4f acc[4][4];
#pragma unroll
  for (int a=0;a<4;++a)
#pragma unroll
    for (int b=0;b<4;++b) acc[a][b] = z;
  for (int c=0; c<8; ++c){
    __syncthreads();
    { int r=t>>2, sg=t&3;
      *(v8s*)&lA[r*40+sg*8] = *(const v8s*)(x_bf + (row0+r)*ND + c*32 + sg*8); }
#pragma unroll
    for (int it2=0; it2<2; ++it2){
      int s2=t+it2*512; int n=s2>>2, sg=s2&3;
      *(v8s*)&lB[n*40+sg*8] = *(const v8s*)(wt1a + n*ND + c*32 + sg*8);
    }
    __syncthreads();
    v8s a[4], b[4];
#pragma unroll
    for (int mf=0;mf<4;++mf) a[mf] = *(v8s*)&lA[(wm*64+mf*16+lr)*40 + lg*8];
#pragma unroll
    for (int nf=0;nf<4;++nf) b[nf] = *(v8s*)&lB[(wn*64+nf*16+lr)*40 + lg*8];
#pragma unroll
    for (int mf=0;mf<4;++mf)
#pragma unroll
      for (int nf=0;nf<4;++nf)
        acc[mf][nf] = __builtin_amdgcn_mfma_f32_16x16x32_bf16(a[mf], b[nf], acc[mf][nf], 0,0,0);
  }
#pragma unroll
  for (int mf=0;mf<4;++mf)
#pragma unroll
    for (int nf=0;nf<4;++nf)
#pragma unroll
      for (int r=0;r<4;++r){
        int rr = wm*64+mf*16+lg*4+r, cc = wn*64+nf*16+lr;
        P[(row0+rr)*ND + cc] = f2b(acc[mf][nf][r] + b_t1[cc]);
      }
}

// ------ fused dynamics, phase-reordered so ONE acc set is live at a time -----
// j0-7:  ev@wt1b -> acc2  -> u=SiLU(acc2+P) in lU      (acc2 dies)
// j8-15: u@wt2   -> acc4  -> tau bf16 into lU at j=16  (acc4 dies; u dead)
// j16-23: x@weff_ih ; j24-31: ev@weff_hh -> accI -> epilogue (o overwrites accI)
template<int BASEF, int WF, int WT, int WB>
__launch_bounds__(512,2)
__global__ void k_dyn5(const u16* __restrict__ x_bf, const u16* __restrict__ ev_bf,
                       const float* __restrict__ baseF,
                       const u16* __restrict__ weff_ih, const u16* __restrict__ weff_hh,
                       const u16* __restrict__ wt1b, const u16* __restrict__ wt2,
                       const u16* __restrict__ P,
                       const float* __restrict__ b_ih, const float* __restrict__ b_hh,
                       const float* __restrict__ b_t2, float coef,
                       float* __restrict__ outF, u16* __restrict__ outB, u16* __restrict__ outT){
  __shared__ u16 lA[3*4096];       // 3 x [128][32] linear (gload_lds dest)
  __shared__ u16 lB[3*8192];       // 3 x [256][32] linear
  __shared__ u16 lU[128*272];      // u -> tau -> output bounce (serial reuse)
  __shared__ float sb1[256], sb2[256];
  const int t = threadIdx.x, lid = t&63, wid = t>>6;
  const int wm = wid>>2, wn = wid&3, lr = lid&15, lg = lid>>4;
  const long row0 = (long)blockIdx.x*128;

  if (t < 256){ sb1[t] = b_ih[t] + b_hh[t]; sb2[t] = b_t2[t]; }

  // staging source offsets (chunk-XOR pre-swizzled on the GLOBAL side)
  const int rA  = wid*16 + (lid>>2);                   // 0..127
  const long aoffg = (row0 + rA)*ND + (((lid&3) ^ ((rA>>1)&3))*8);
  const int rB0 = wid*32 + (lid>>2), rB1 = rB0 + 16;
  const int boffg0 = rB0*ND + (((lid&3) ^ ((rB0>>1)&3))*8);
  const int boffg1 = rB1*ND + (((lid&3) ^ ((rB1>>1)&3))*8);

  // fragment read offsets (u16 index within a slot), same XOR on the read side
  int aoff[4], boff[4], uoff[4];
#pragma unroll
  for (int mf=0;mf<4;++mf){
    int R = wm*64 + mf*16 + lr;
    aoff[mf] = R*32 + ((lg ^ ((R>>1)&3))*8);
    uoff[mf] = R*272 + ((lg ^ ((R>>1)&3))*8);
  }
#pragma unroll
  for (int nf=0;nf<4;++nf){
    int N = wn*64 + nf*16 + lr;
    boff[nf] = N*32 + ((lg ^ ((N>>1)&3))*8);
  }

  // loads per job: jj<8 ->3 ; 8..15 ->2 (no A) ; 16..31 ->3
  auto stage = [&](int jj, int sl){
    const int c = (jj&7)*32;
    if (jj < 8)                    async16(ev_bf + aoffg + c, lA + sl*4096 + wid*512);
    else if (jj >= 16 && jj < 24)  async16(x_bf  + aoffg + c, lA + sl*4096 + wid*512);
    else if (jj >= 24)             async16(ev_bf + aoffg + c, lA + sl*4096 + wid*512);
    const u16* W = (jj<8) ? wt1b : (jj<16 ? wt2 : (jj<24 ? weff_ih : weff_hh));
    async16(W + c + boffg0, lB + sl*8192 + wid*1024);
    async16(W + c + boffg1, lB + sl*8192 + wid*1024 + 512);
  };

  // prologue: jobs 0,1 staged; P prefetch; full drain
  stage(0,0); stage(1,1);
  u16 Pv[64];
#pragma unroll
  for (int mf=0;mf<4;++mf)
#pragma unroll
    for (int nf=0;nf<4;++nf)
#pragma unroll
      for (int r=0;r<4;++r){
        int rr = wm*64+mf*16+lg*4+r, cc = wn*64+nf*16+lr;
        Pv[(mf*4+nf)*4+r] = P[(row0+rr)*ND + cc];
      }
  __syncthreads();

  v4f z = {0.f,0.f,0.f,0.f};

  // ---- phase 1: j=0..7  acc2 = ev@wt1b ----
  {
    v4f acc2[4][4];
#pragma unroll
    for (int a=0;a<4;++a)
#pragma unroll
      for (int b=0;b<4;++b) acc2[a][b]=z;
#pragma unroll
    for (int j=0; j<8; ++j){
      waitv(j<7 ? 3 : 2);            // N_j = L(j+1)
      __builtin_amdgcn_s_barrier();
      stage(j+2, (j+2)%3);
      const int rs = j%3;
      v8s b[4], a[4];
#pragma unroll
      for (int nf=0;nf<4;++nf) b[nf] = *(v8s*)&lB[rs*8192 + boff[nf]];
#pragma unroll
      for (int mf=0;mf<4;++mf) a[mf] = *(v8s*)&lA[rs*4096 + aoff[mf]];
      __builtin_amdgcn_s_setprio(1);
#pragma unroll
      for (int mf=0;mf<4;++mf)
#pragma unroll
        for (int nf=0;nf<4;++nf)
          acc2[mf][nf] = __builtin_amdgcn_mfma_f32_16x16x32_bf16(a[mf], b[nf], acc2[mf][nf], 0,0,0);
      __builtin_amdgcn_s_setprio(0);
    }
    // u = SiLU(acc2 + P) -> lU  (acc2 dies here)
#pragma unroll
    for (int mf=0;mf<4;++mf)
#pragma unroll
      for (int nf=0;nf<4;++nf)
#pragma unroll
        for (int r=0;r<4;++r){
          int rr = wm*64+mf*16+lg*4+r, cc = wn*64+nf*16+lr;
          float v = acc2[mf][nf][r] + b2f(Pv[(mf*4+nf)*4+r]);
          float sgm = 1.f/(1.f + __expf(-v));
          int w = cc>>5, ch = (cc>>3)&3;
          lU[rr*272 + w*32 + ((ch ^ ((rr>>1)&3))*8) + (cc&7)] = f2b(v*sgm);
        }
    asm volatile("s_waitcnt lgkmcnt(0)" ::: "memory");
  }

  // ---- phase 2: j=8..15  acc4 = u@wt2 ----
  v4f acc4[4][4];
#pragma unroll
  for (int a=0;a<4;++a)
#pragma unroll
    for (int b=0;b<4;++b) acc4[a][b]=z;
#pragma unroll
  for (int j=8; j<16; ++j){
    waitv(j<15 ? 2 : 3);             // N_j = L(j+1)
    __builtin_amdgcn_s_barrier();
    stage(j+2, (j+2)%3);
    const int rs = j%3;
    v8s b[4], a[4];
#pragma unroll
    for (int nf=0;nf<4;++nf) b[nf] = *(v8s*)&lB[rs*8192 + boff[nf]];
#pragma unroll
    for (int mf=0;mf<4;++mf) a[mf] = *(v8s*)&lU[uoff[mf] + (j-8)*32];
    __builtin_amdgcn_s_setprio(1);
#pragma unroll
    for (int mf=0;mf<4;++mf)
#pragma unroll
      for (int nf=0;nf<4;++nf)
        acc4[mf][nf] = __builtin_amdgcn_mfma_f32_16x16x32_bf16(a[mf], b[nf], acc4[mf][nf], 0,0,0);
    __builtin_amdgcn_s_setprio(0);
  }

  // ---- phase 3: j=16..31  accI = x@weff_ih + ev@weff_hh ----
  v4f accI[4][4];
#pragma unroll
  for (int a=0;a<4;++a)
#pragma unroll
    for (int b=0;b<4;++b) accI[a][b]=z;
#pragma unroll
  for (int j=16; j<32; ++j){
    waitv(j<=30 ? 3 : 0);
    __builtin_amdgcn_s_barrier();
    if (j <= 29) stage(j+2, (j+2)%3);
    if (j == 16){
      // tau = softplus(acc4 + b_t2) + TAU_MIN -> bf16 into lU (u is dead; acc4 dies)
#pragma unroll
      for (int mf=0;mf<4;++mf)
#pragma unroll
        for (int nf=0;nf<4;++nf)
#pragma unroll
          for (int r=0;r<4;++r){
            int rr = wm*64+mf*16+lg*4+r, cc = wn*64+nf*16+lr;
            float zz = acc4[mf][nf][r] + sb2[cc];
            float sp = (zz > 15.f) ? zz : __logf(1.f + __expf(zz));
            int w = cc>>5, ch = (cc>>3)&3;
            lU[rr*272 + w*32 + ((ch ^ ((rr>>1)&3))*8) + (cc&7)] = f2b(sp + TAU_MIN);
          }
    }
    const int rs = j%3;
    v8s b[4], a[4];
#pragma unroll
    for (int nf=0;nf<4;++nf) b[nf] = *(v8s*)&lB[rs*8192 + boff[nf]];
#pragma unroll
    for (int mf=0;mf<4;++mf) a[mf] = *(v8s*)&lA[rs*4096 + aoff[mf]];
    __builtin_amdgcn_s_setprio(1);
#pragma unroll
    for (int mf=0;mf<4;++mf)
#pragma unroll
      for (int nf=0;nf<4;++nf)
        accI[mf][nf] = __builtin_amdgcn_mfma_f32_16x16x32_bf16(a[mf], b[nf], accI[mf][nf], 0,0,0);
    __builtin_amdgcn_s_setprio(0);
  }

  __syncthreads();   // tau writes drained; everyone past the loop

  // epilogue: inter = tanh(accI+b); o = bv + coef*(inter-ev)/tau  (o -> accI)
#pragma unroll
  for (int mf=0;mf<4;++mf)
#pragma unroll
    for (int nf=0;nf<4;++nf)
#pragma unroll
      for (int r=0;r<4;++r){
        int rr = wm*64+mf*16+lg*4+r, cc = wn*64+nf*16+lr;
        long gi = (row0+rr)*ND + cc;
        float pre = accI[mf][nf][r] + sb1[cc];
        float pc = fminf(fmaxf(pre, -15.f), 15.f);
        float e2 = __expf(2.f*pc);
        float inter = (e2 - 1.f)/(e2 + 1.f);
        int w = cc>>5, ch = (cc>>3)&3;
        float tau = b2f(lU[rr*272 + w*32 + ((ch ^ ((rr>>1)&3))*8) + (cc&7)]);
        float bv, ev;
        if (BASEF){ bv = baseF[gi]; ev = b2f(ev_bf[gi]); }
        else      { bv = b2f(ev_bf[gi]); ev = bv; }
        float o = bv + coef*(inter - ev)/tau;
        if (WF) outF[gi] = o;
        accI[mf][nf][r] = o;
      }

  if (WT || WB) __syncthreads();   // all tau reads done before lU overwrite

  if (WT){
    // transpose bounce: lU as [256 cols][136 rows]
#pragma unroll
    for (int mf=0;mf<4;++mf)
#pragma unroll
      for (int nf=0;nf<4;++nf)
#pragma unroll
        for (int r=0;r<4;++r){
          int rr = wm*64+mf*16+lg*4+r, cc = wn*64+nf*16+lr;
          lU[cc*136 + rr] = f2b(accI[mf][nf][r]);
        }
    __syncthreads();
    { int col = t>>1, h0 = (t&1)*64;
#pragma unroll
      for (int e=0;e<8;++e)
        *(v8s*)(outT + (long)col*NB + row0 + h0 + e*8) = *(v8s*)&lU[col*136 + h0 + e*8];
    }
  }
  if (WB){
    if (WT) __syncthreads();
    // row-major bounce: lU as [128][256]
#pragma unroll
    for (int mf=0;mf<4;++mf)
#pragma unroll
      for (int nf=0;nf<4;++nf)
#pragma unroll
        for (int r=0;r<4;++r){
          int rr = wm*64+mf*16+lg*4+r, cc = wn*64+nf*16+lr;
          lU[rr*256 + cc] = f2b(accI[mf][nf][r]);
        }
    __syncthreads();
    { int row = t>>2, c0 = (t&3)*64;
#pragma unroll
      for (int e=0;e<8;++e)
        *(v8s*)(outB + (row0 + row)*ND + c0 + e*8) = *(v8s*)&lU[row*256 + c0 + e*8];
    }
  }
}

// ---------------- hebb partial: part[blk] = A^T-chunk @ hm-chunk (pipelined) --
__launch_bounds__(512,2)
__global__ void k_hebb_part2(const u16* __restrict__ xT, const u16* __restrict__ hmT,
                             u16* __restrict__ part){
  __shared__ u16 lA[4*8192];    // 4 x [256][32]
  __shared__ u16 lB[4*8192];
  const int t = threadIdx.x, lid = t&63, wid = t>>6;
  const int wm = wid>>2, wn = wid&3, lr = lid&15, lg = lid>>4;
  const int mat = blockIdx.x & 1, chunk = blockIdx.x >> 1;   // 128 chunks x 2 mats
  const u16* Asrc = mat ? hmT : xT;
  const long col0 = (long)chunk*256;

  const int r0s = wid*32 + (lid>>2), r1s = r0s + 16;
  const long goff0 = (long)r0s*NB + (((lid&3) ^ ((r0s>>1)&3))*8);
  const long goff1 = (long)r1s*NB + (((lid&3) ^ ((r1s>>1)&3))*8);

  int aoff[8], boff[4];
#pragma unroll
  for (int mf=0;mf<8;++mf){
    int R = wm*128 + mf*16 + lr;
    aoff[mf] = R*32 + ((lg ^ ((R>>1)&3))*8);
  }
#pragma unroll
  for (int nf=0;nf<4;++nf){
    int N = wn*64 + nf*16 + lr;
    boff[nf] = N*32 + ((lg ^ ((N>>1)&3))*8);
  }

  auto stage = [&](int kc, int sl){
    const long c = col0 + kc*32;
    async16(Asrc + goff0 + c, lA + sl*8192 + wid*1024);
    async16(Asrc + goff1 + c, lA + sl*8192 + wid*1024 + 512);
    async16(hmT  + goff0 + c, lB + sl*8192 + wid*1024);
    async16(hmT  + goff1 + c, lB + sl*8192 + wid*1024 + 512);
  };

  stage(0,0); stage(1,1); stage(2,2);
  __syncthreads();

  v4f z = {0.f,0.f,0.f,0.f};
  v4f acc[8][4];
#pragma unroll
  for (int a=0;a<8;++a)
#pragma unroll
    for (int b=0;b<4;++b) acc[a][b] = z;

#pragma unroll
  for (int j=0; j<8; ++j){
    int m2 = 7-j; if (m2 > 2) m2 = 2;
    waitv(m2*4);
    __builtin_amdgcn_s_barrier();
    if (j <= 4) stage(j+3, (j+3)&3);
    const int rs = j&3;
    v8s a[8], b[4];
#pragma unroll
    for (int mf=0;mf<8;++mf) a[mf] = *(v8s*)&lA[rs*8192 + aoff[mf]];
#pragma unroll
    for (int nf=0;nf<4;++nf) b[nf] = *(v8s*)&lB[rs*8192 + boff[nf]];
    __builtin_amdgcn_s_setprio(1);
#pragma unroll
    for (int mf=0;mf<8;++mf)
#pragma unroll
      for (int nf=0;nf<4;++nf)
        acc[mf][nf] = __builtin_amdgcn_mfma_f32_16x16x32_bf16(a[mf], b[nf], acc[mf][nf], 0,0,0);
    __builtin_amdgcn_s_setprio(0);
  }

  u16* dst = part + (long)blockIdx.x*65536;
#pragma unroll
  for (int mf=0;mf<8;++mf)
#pragma unroll
    for (int nf=0;nf<4;++nf)
#pragma unroll
      for (int r=0;r<4;++r){
        int i = wm*128+mf*16+lg*4+r, jj = wn*64+nf*16+lr;
        dst[i*ND + jj] = f2b(acc[mf][nf][r]);
      }
}

// ---------------- hebb reduce + Weff rebuild ----------------
__global__ void k_hebb_reduce(const u16* __restrict__ part,
                              const float* __restrict__ prev_ih, const float* __restrict__ prev_hh,
                              float* __restrict__ next_ih, float* __restrict__ next_hh,
                              const float* __restrict__ W_ih, const float* __restrict__ W_hh,
                              u16* __restrict__ weff_ih, u16* __restrict__ weff_hh){
  int tid = blockIdx.x*blockDim.x + threadIdx.x;
  if (tid >= 2*ND*ND) return;
  int mat = tid >> 16;
  int rem = tid & 65535;
  float s = 0.f;
  for (int c=0; c<128; ++c) s += b2f(part[(long)((c<<1)+mat)*65536 + rem]);
  const float* prev = mat ? prev_hh : prev_ih;
  float nv = DECAY*prev[rem] + HEBB_SCALE*s;
  if (mat) next_hh[rem] = nv; else next_ih[rem] = nv;
  int k = rem >> 8, n = rem & 255;
  const float* Wb = mat ? W_hh : W_ih;
  u16 wv = f2b(Wb[n*ND + k] + ALPHA*nv);
  if (mat) weff_hh[n*ND + k] = wv; else weff_ih[n*ND + k] = wv;
}

// ---------------- launcher ----------------
extern "C" void kernel_launch(void* const* d_in, const int* in_sizes, int n_in,
                              void* d_out, int out_size, void* d_ws, size_t ws_size,
                              hipStream_t stream) {
  const float* x       = (const float*)d_in[0];
  const float* h       = (const float*)d_in[1];
  const float* hebb_ih = (const float*)d_in[2];
  const float* hebb_hh = (const float*)d_in[3];
  const float* W_ih    = (const float*)d_in[4];
  const float* b_ih    = (const float*)d_in[5];
  const float* W_hh    = (const float*)d_in[6];
  const float* b_hh    = (const float*)d_in[7];
  const float* W_t1    = (const float*)d_in[8];
  const float* b_t1    = (const float*)d_in[9];
  const float* W_t2    = (const float*)d_in[10];
  const float* b_t2    = (const float*)d_in[11];
  float* h_state = (float*)d_out;

  char* w = (char*)d_ws;
  u16* x_bf  = (u16*)w;  w += 16777216;
  u16* xT    = (u16*)w;  w += 16777216;
  u16* P     = (u16*)w;  w += 16777216;
  u16* hmT   = (u16*)w;  w += 16777216;
  u16* h_bf  = (u16*)w;  w += 16777216;
  u16* hm_bf = (u16*)w;  w += 16777216;
  u16* part  = (u16*)w;  w += 33554432;     // 256 slabs x 64K x 2B
  float* hebA_ih = (float*)w; w += 262144;
  float* hebA_hh = (float*)w; w += 262144;
  float* hebB_ih = (float*)w; w += 262144;
  float* hebB_hh = (float*)w; w += 262144;
  u16* weff_ih = (u16*)w; w += 131072;
  u16* weff_hh = (u16*)w; w += 131072;
  u16* wt1a    = (u16*)w; w += 131072;
  u16* wt1b    = (u16*)w; w += 131072;
  u16* wt2     = (u16*)w; w += 131072;
  if ((size_t)(w - (char*)d_ws) > ws_size) return;

  k_init<<<512,256,0,stream>>>(x, h, x_bf, h_bf, xT);
  k_prep_w<<<256,256,0,stream>>>(W_ih,W_hh,W_t1,W_t2,hebb_ih,hebb_hh,
                                 weff_ih,weff_hh,wt1a,wt1b,wt2);
  k_gemmP<<<256,512,0,stream>>>(x_bf, wt1a, b_t1, P);

  const float* pih = hebb_ih; const float* phh = hebb_hh;
  for (int s=0; s<3; ++s){
    float* nih = (s&1) ? hebB_ih : hebA_ih;
    float* nhh = (s&1) ? hebB_hh : hebA_hh;
    // k1: h_mid = h + 0.5*DT*dynamics(h)  (bf16 state path; writes hm_bf + hmT)
    k_dyn5<0,0,1,1><<<256,512,0,stream>>>(x_bf, h_bf, (const float*)0,
                                          weff_ih, weff_hh, wt1b, wt2, P,
                                          b_ih, b_hh, b_t2, 0.5f*DTF,
                                          (float*)0, hm_bf, hmT);
    // hebb updates + Weff rebuild
    k_hebb_part2<<<256,512,0,stream>>>(xT, hmT, part);
    k_hebb_reduce<<<512,256,0,stream>>>(part, pih, phh, nih, nhh, W_ih, W_hh, weff_ih, weff_hh);
    // k2: h = h + DT*dynamics(h_mid)  (baseF = h input on step 0, else h_state)
    const float* base = (s==0) ? h : (const float*)h_state;
    if (s < 2)
      k_dyn5<1,1,0,1><<<256,512,0,stream>>>(x_bf, hm_bf, base,
                                            weff_ih, weff_hh, wt1b, wt2, P,
                                            b_ih, b_hh, b_t2, DTF,
                                            h_state, h_bf, (u16*)0);
    else
      k_dyn5<1,1,0,0><<<256,512,0,stream>>>(x_bf, hm_bf, base,
                                            weff_ih, weff_hh, wt1b, wt2, P,
                                            b_ih, b_hh, b_t2, DTF,
                                            h_state, (u16*)0, (u16*)0);
    pih = nih; phh = nhh;
  }
}